// Round 4
// baseline (3186.243 us; speedup 1.0000x reference)
//
#include <hip/hip_runtime.h>
#include <math.h>

// Problem constants
#define B_SZ 256
#define S_SZ 6
#define D_SZ 10000
#define DP   10112      // D padded to 158*64
#define C_SZ 128
#define K_SZ 500
#define KP   512        // codebook rows padded (8 k-tiles of 64)
#define NIT  (DP / 64)  // 158 K-iterations

typedef _Float16     half8  __attribute__((ext_vector_type(8)));
typedef float        f32x4  __attribute__((ext_vector_type(4)));
typedef unsigned int u32x4v __attribute__((ext_vector_type(4)));

__device__ __forceinline__ void stage16(const void* g, void* l) {
    __builtin_amdgcn_global_load_lds(
        (const __attribute__((address_space(1))) unsigned int*)g,
        (__attribute__((address_space(3))) unsigned int*)l, 16, 0, 0);
}

// ---- prep: split W_reg (fp32) into f16 hi + f16 lo*4096 ----
__global__ void prep_wsplit(const float* __restrict__ wreg,
                            _Float16* __restrict__ whi, _Float16* __restrict__ wlo) {
    int t = blockIdx.x * 256 + threadIdx.x;
    if (t >= C_SZ * DP) return;
    int c = t / DP, d = t - c * DP;
    float w = (d < D_SZ) ? wreg[c * D_SZ + d] : 0.0f;
    _Float16 hi = (_Float16)w;
    float r = w - (float)hi;
    _Float16 lo = (_Float16)(r * 4096.0f);
    whi[t] = hi;
    wlo[t] = lo;
}

// ---- prep: codebook (±1 fp32) -> f16, zero-padded to [512][DP] ----
__global__ void prep_cb(const float* __restrict__ cb, _Float16* __restrict__ cbp) {
    int t = blockIdx.x * 256 + threadIdx.x;
    if (t >= KP * DP) return;
    int k = t / DP, d = t - k * DP;
    float v = (k < K_SZ && d < D_SZ) ? cb[k * D_SZ + d] : 0.0f;
    cbp[t] = (_Float16)v;
}

// ---- prep: enc sign mask (0x0000 = +1, 0x8000 = -1), fp64 for exact sign match ----
__global__ void prep_enc(const float* __restrict__ x, const float* __restrict__ wp,
                         const float* __restrict__ bp, unsigned short* __restrict__ em) {
    int t = blockIdx.x * 256 + threadIdx.x;
    if (t >= B_SZ * DP) return;
    int b = t / DP, d = t - b * DP;
    unsigned short m = 0;
    if (d < D_SZ) {
        double p = 0.0;
        #pragma unroll
        for (int s = 0; s < S_SZ; ++s)
            p += (double)x[b * S_SZ + s] * (double)wp[d * S_SZ + s];
        double hv = cos(p + (double)bp[d]) * sin(p);
        m = (hv > 0.0) ? (unsigned short)0u : (unsigned short)0x8000u;
    }
    em[t] = m;
}

// ---- main: block = 512 thr = 8 waves = (split x kh x ch); tile 4b x 64c x 64k.
// Each wave computes ONE split (hi or lo) of a 4b x 32c x 32k sub-tile -> 64 acc
// regs/wave -> 4 waves/SIMD with launch_bounds(512,4). Signs XORed onto B (cb)
// fragments (bit-exact); sign masks read directly from GLOBAL (off the LDS pipe).
// LDS XOR-swizzled: 16-B chunk p of row r holds logical chunk (p ^ (r&7)).
__global__ __launch_bounds__(512, 4) void gemm_argmax(
    const _Float16* __restrict__ whi, const _Float16* __restrict__ wlo,
    const _Float16* __restrict__ cbp, const unsigned short* __restrict__ em,
    float* __restrict__ pval, int* __restrict__ pidx)
{
    const int kt = blockIdx.x >> 1;   // 0..7  k-tile (64 codebook rows)
    const int ct = blockIdx.x & 1;    // 0..1  c-tile (64 classes)
    const int bg = blockIdx.y;        // 0..63 batch group (4 batches)
    const int tid   = threadIdx.x;
    const int wave  = tid >> 6;
    const int lane  = tid & 63;
    const int quad  = lane >> 4;
    const int col   = lane & 15;
    const int ch    = wave & 1;         // c half (32 rows)
    const int kh    = (wave >> 1) & 1;  // k half (32 cols)
    const int split = wave >> 2;        // 0 = hi, 1 = lo

    __shared__ __align__(16) _Float16 s_all[3 * 4096];  // whi | wlo | cb, 8 KB each
    __shared__ __align__(16) float s_argv[4 * 2 * 64];  // [b][kh][crow]
    __shared__ __align__(16) int   s_argi[4 * 2 * 64];

    _Float16* s_whi = s_all;
    _Float16* s_wlo = s_all + 4096;
    _Float16* s_cb  = s_all + 8192;

    f32x4 acc[4][2][2];
    #pragma unroll
    for (int b = 0; b < 4; ++b)
        #pragma unroll
        for (int m = 0; m < 2; ++m)
            #pragma unroll
            for (int n = 0; n < 2; ++n)
                acc[b][m][n] = (f32x4){0.f, 0.f, 0.f, 0.f};

    const int c0  = ct * 64;
    const int kr0 = kt * 64;
    const int bg4 = bg * 4;

    // staging: each thread stages exactly one 16-B chunk of each array per iter
    const int srow = tid >> 3;
    const int sp   = tid & 7;
    const int sgc  = (sp ^ (srow & 7)) * 8;       // swizzled global f16 col
    const size_t aoff = (size_t)(c0 + srow) * DP + sgc;
    const size_t boff = (size_t)(kr0 + srow) * DP + sgc;
    const int soff = tid * 8;

    const _Float16* asrc = split ? s_wlo : s_whi;
    const unsigned short* em_b = em + (size_t)bg4 * DP;

    // LDS fragment row bases (f16 units)
    const int arow0 = (ch * 32 + col) * 64;
    const int arow1 = (ch * 32 + 16 + col) * 64;
    const int brow0 = (kh * 32 + col) * 64;
    const int brow1 = (kh * 32 + 16 + col) * 64;

    for (int kb = 0; kb < NIT; ++kb) {
        const int k0 = kb * 64;
        stage16(whi + aoff + k0, s_whi + soff);
        stage16(wlo + aoff + k0, s_wlo + soff);
        stage16(cbp + boff + k0, s_cb  + soff);
        __syncthreads();

        #pragma unroll
        for (int k2 = 0; k2 < 2; ++k2) {
            const int chunk = k2 * 4 + quad;
            const int sw    = (chunk ^ (col & 7)) * 8;
            const u32x4v a0 = *(const u32x4v*)(asrc + arow0 + sw);
            const u32x4v a1 = *(const u32x4v*)(asrc + arow1 + sw);
            const u32x4v b0 = *(const u32x4v*)(s_cb + brow0 + sw);
            const u32x4v b1 = *(const u32x4v*)(s_cb + brow1 + sw);
            const half8 af0 = __builtin_bit_cast(half8, a0);
            const half8 af1 = __builtin_bit_cast(half8, a1);
            const unsigned short* em_k = em_b + k0 + chunk * 8;
            #pragma unroll
            for (int b = 0; b < 4; ++b) {
                const u32x4v mr = *(const u32x4v*)(em_k + b * DP);  // global, quad-uniform
                const half8 bs0 = __builtin_bit_cast(half8, b0 ^ mr);
                const half8 bs1 = __builtin_bit_cast(half8, b1 ^ mr);
                acc[b][0][0] = __builtin_amdgcn_mfma_f32_16x16x32_f16(af0, bs0, acc[b][0][0], 0, 0, 0);
                acc[b][0][1] = __builtin_amdgcn_mfma_f32_16x16x32_f16(af0, bs1, acc[b][0][1], 0, 0, 0);
                acc[b][1][0] = __builtin_amdgcn_mfma_f32_16x16x32_f16(af1, bs0, acc[b][1][0], 0, 0, 0);
                acc[b][1][1] = __builtin_amdgcn_mfma_f32_16x16x32_f16(af1, bs1, acc[b][1][1], 0, 0, 0);
            }
        }
        __syncthreads();
    }

    // ---- epilogue: combine hi + lo*2^-12 via LDS (per b), then partial argmax ----
    // C/D layout (16x16): col = lane&15 (k), row = quad*4 + reg (c)
    float* fs = (float*)s_all;  // 4096 f32 = 16 KB scratch, region per (kh,ch)
    const int reg0 = (kh * 2 + ch) * 1024;
    #pragma unroll 1
    for (int b = 0; b < 4; ++b) {
        if (split == 1) {
            #pragma unroll
            for (int m = 0; m < 2; ++m)
                #pragma unroll
                for (int n = 0; n < 2; ++n)
                    *(f32x4*)(fs + reg0 + (m * 2 + n) * 256 + lane * 4) =
                        acc[b][m][n] * 0.000244140625f;  // lo * 2^-12 (exact)
        }
        __syncthreads();
        if (split == 0) {
            f32x4 s[2][2];
            #pragma unroll
            for (int m = 0; m < 2; ++m)
                #pragma unroll
                for (int n = 0; n < 2; ++n)
                    s[m][n] = acc[b][m][n] +
                              *(const f32x4*)(fs + reg0 + (m * 2 + n) * 256 + lane * 4);
            #pragma unroll
            for (int m = 0; m < 2; ++m) {
                #pragma unroll
                for (int r = 0; r < 4; ++r) {
                    float bv = -3.0e38f; int bk = 0x7fffffff;
                    #pragma unroll
                    for (int n = 0; n < 2; ++n) {
                        int kg = kr0 + kh * 32 + n * 16 + col;
                        float v = s[m][n][r];
                        if (kg < K_SZ && v > bv) { bv = v; bk = kg; }
                    }
                    #pragma unroll
                    for (int off = 1; off < 16; off <<= 1) {
                        float ov = __shfl_xor(bv, off, 64);
                        int   ok = __shfl_xor(bk, off, 64);
                        if (ov > bv || (ov == bv && ok < bk)) { bv = ov; bk = ok; }
                    }
                    if (col == 0) {
                        int crow = ch * 32 + m * 16 + quad * 4 + r;
                        s_argv[(b * 2 + kh) * 64 + crow] = bv;
                        s_argi[(b * 2 + kh) * 64 + crow] = bk;
                    }
                }
            }
        }
        __syncthreads();
    }
    if (tid < 256) {
        int b = tid >> 6, crow = tid & 63;
        float v0 = s_argv[(b * 2 + 0) * 64 + crow], v1 = s_argv[(b * 2 + 1) * 64 + crow];
        int   i0 = s_argi[(b * 2 + 0) * 64 + crow], i1 = s_argi[(b * 2 + 1) * 64 + crow];
        float bv; int bk;
        if (v1 > v0 || (v1 == v0 && i1 < i0)) { bv = v1; bk = i1; }
        else                                  { bv = v0; bk = i0; }
        int o = ((bg4 + b) * 8 + kt) * 128 + (c0 + crow);
        pval[o] = bv;
        pidx[o] = bk;
    }
}

// ---- final: reduce 8 kt partials per (b,c), map index -> temperature ----
__global__ void finalize_pred(const float* __restrict__ pval, const int* __restrict__ pidx,
                              float* __restrict__ out) {
    int t = blockIdx.x * 256 + threadIdx.x;
    if (t >= B_SZ * C_SZ) return;
    int b = t >> 7, c = t & 127;
    float bv = -3.0e38f; int bk = 0;
    #pragma unroll
    for (int nt = 0; nt < 8; ++nt) {
        int o = (b * 8 + nt) * 128 + c;
        float v = pval[o]; int k = pidx[o];
        if (v > bv || (v == bv && k < bk)) { bv = v; bk = k; }
    }
    out[t] = (float)bk / 499.0f * 61.5f + (-19.9f);
}

extern "C" void kernel_launch(void* const* d_in, const int* in_sizes, int n_in,
                              void* d_out, int out_size, void* d_ws, size_t ws_size,
                              hipStream_t stream) {
    const float* x    = (const float*)d_in[0];
    const float* wp   = (const float*)d_in[1];
    const float* bp   = (const float*)d_in[2];
    const float* wreg = (const float*)d_in[3];
    const float* cb   = (const float*)d_in[4];
    float* out = (float*)d_out;

    char* ws = (char*)d_ws;
    size_t o = 0;
    auto take = [&](size_t bytes) -> char* {
        o = (o + 255) & ~(size_t)255;
        char* p = ws + o;
        o += bytes;
        return p;
    };
    _Float16* whi       = (_Float16*)take(sizeof(_Float16) * C_SZ * DP);
    _Float16* wlo       = (_Float16*)take(sizeof(_Float16) * C_SZ * DP);
    _Float16* cbp       = (_Float16*)take(sizeof(_Float16) * KP * DP);
    unsigned short* em  = (unsigned short*)take(sizeof(unsigned short) * B_SZ * DP);
    float* pv           = (float*)take(sizeof(float) * B_SZ * 8 * C_SZ);
    int*   pi           = (int*)take(sizeof(int) * B_SZ * 8 * C_SZ);
    (void)ws_size; (void)in_sizes; (void)n_in; (void)out_size;

    prep_wsplit<<<(C_SZ * DP + 255) / 256, 256, 0, stream>>>(wreg, whi, wlo);
    prep_cb<<<(KP * DP + 255) / 256, 256, 0, stream>>>(cb, cbp);
    prep_enc<<<(B_SZ * DP + 255) / 256, 256, 0, stream>>>(x, wp, bp, em);

    dim3 g(16, 64);  // x: kt*2+ct, y: batch group
    gemm_argmax<<<g, 512, 0, stream>>>(whi, wlo, cbp, em, pv, pi);

    finalize_pred<<<(B_SZ * C_SZ + 255) / 256, 256, 0, stream>>>(pv, pi, out);
}

// Round 5
// 3107.498 us; speedup vs baseline: 1.0253x; 1.0253x over previous
//
#include <hip/hip_runtime.h>
#include <math.h>

// Problem constants
#define B_SZ 256
#define S_SZ 6
#define D_SZ 10000
#define DP   10112      // D padded to 158*64
#define C_SZ 128
#define K_SZ 500
#define KP   512        // codebook rows padded (8 k-tiles of 64)
#define NIT  (DP / 64)  // 158 K-iterations

typedef _Float16     half8  __attribute__((ext_vector_type(8)));
typedef float        f32x4  __attribute__((ext_vector_type(4)));
typedef unsigned int u32x4v __attribute__((ext_vector_type(4)));

__device__ __forceinline__ void stage16(const void* g, void* l) {
    __builtin_amdgcn_global_load_lds(
        (const __attribute__((address_space(1))) unsigned int*)g,
        (__attribute__((address_space(3))) unsigned int*)l, 16, 0, 0);
}

// ---- prep: split W_reg (fp32) into f16 hi + f16 lo*4096 ----
__global__ void prep_wsplit(const float* __restrict__ wreg,
                            _Float16* __restrict__ whi, _Float16* __restrict__ wlo) {
    int t = blockIdx.x * 256 + threadIdx.x;
    if (t >= C_SZ * DP) return;
    int c = t / DP, d = t - c * DP;
    float w = (d < D_SZ) ? wreg[c * D_SZ + d] : 0.0f;
    _Float16 hi = (_Float16)w;
    float r = w - (float)hi;
    _Float16 lo = (_Float16)(r * 4096.0f);
    whi[t] = hi;
    wlo[t] = lo;
}

// ---- prep: codebook (±1 fp32) -> f16, zero-padded to [512][DP] ----
__global__ void prep_cb(const float* __restrict__ cb, _Float16* __restrict__ cbp) {
    int t = blockIdx.x * 256 + threadIdx.x;
    if (t >= KP * DP) return;
    int k = t / DP, d = t - k * DP;
    float v = (k < K_SZ && d < D_SZ) ? cb[k * D_SZ + d] : 0.0f;
    cbp[t] = (_Float16)v;
}

// ---- prep: enc sign mask (0x0000 = +1, 0x8000 = -1), fp64 for exact sign match ----
__global__ void prep_enc(const float* __restrict__ x, const float* __restrict__ wp,
                         const float* __restrict__ bp, unsigned short* __restrict__ em) {
    int t = blockIdx.x * 256 + threadIdx.x;
    if (t >= B_SZ * DP) return;
    int b = t / DP, d = t - b * DP;
    unsigned short m = 0;
    if (d < D_SZ) {
        double p = 0.0;
        #pragma unroll
        for (int s = 0; s < S_SZ; ++s)
            p += (double)x[b * S_SZ + s] * (double)wp[d * S_SZ + s];
        double hv = cos(p + (double)bp[d]) * sin(p);
        m = (hv > 0.0) ? (unsigned short)0u : (unsigned short)0x8000u;
    }
    em[t] = m;
}

// ---- main: block = 512 thr = 8 waves = (split x kh x ch); tile 4b x 64c x 64k.
// Each wave computes ONE split (hi or lo) of a 4b x 32c x 32k sub-tile -> 64 acc
// regs/wave. __launch_bounds__(512,2): empirically (R3/R4) for B=512 the 2nd arg
// k caps VGPRs at 2048/(8k) -> k=2 gives 128-reg cap = 4 waves/SIMD, NO SPILL
// (k=4 gave a 64-reg cap and 20.8 GB of scratch spill traffic).
// Signs XORed onto B (cb) fragments (bit-exact); masks staged in LDS, read as
// quad-broadcast b128. LDS XOR-swizzled: chunk p of row r holds chunk (p^(r&7)).
__global__ __launch_bounds__(512, 2) void gemm_argmax(
    const _Float16* __restrict__ whi, const _Float16* __restrict__ wlo,
    const _Float16* __restrict__ cbp, const unsigned short* __restrict__ em,
    float* __restrict__ pval, int* __restrict__ pidx)
{
    const int kt = blockIdx.x >> 1;   // 0..7  k-tile (64 codebook rows)
    const int ct = blockIdx.x & 1;    // 0..1  c-tile (64 classes)
    const int bg = blockIdx.y;        // 0..63 batch group (4 batches)
    const int tid   = threadIdx.x;
    const int wave  = tid >> 6;
    const int lane  = tid & 63;
    const int quad  = lane >> 4;
    const int col   = lane & 15;
    const int ch    = wave & 1;         // c half (32 rows)
    const int kh    = (wave >> 1) & 1;  // k half (32 cols)
    const int split = wave >> 2;        // 0 = hi, 1 = lo

    __shared__ __align__(16) _Float16 s_all[3 * 4096];  // whi | wlo | cb, 8 KB each
    __shared__ __align__(16) unsigned short s_mask[4 * 64];
    __shared__ __align__(16) float s_argv[4 * 2 * 64];  // [b][kh][crow]
    __shared__ __align__(16) int   s_argi[4 * 2 * 64];

    _Float16* s_whi = s_all;
    _Float16* s_wlo = s_all + 4096;
    _Float16* s_cb  = s_all + 8192;

    f32x4 acc[4][2][2];
    #pragma unroll
    for (int b = 0; b < 4; ++b)
        #pragma unroll
        for (int m = 0; m < 2; ++m)
            #pragma unroll
            for (int n = 0; n < 2; ++n)
                acc[b][m][n] = (f32x4){0.f, 0.f, 0.f, 0.f};

    const int c0  = ct * 64;
    const int kr0 = kt * 64;
    const int bg4 = bg * 4;

    // staging: each thread stages exactly one 16-B chunk of each array per iter
    const int srow = tid >> 3;
    const int sp   = tid & 7;
    const int sgc  = (sp ^ (srow & 7)) * 8;       // swizzled global f16 col
    const size_t aoff = (size_t)(c0 + srow) * DP + sgc;
    const size_t boff = (size_t)(kr0 + srow) * DP + sgc;
    const int soff = tid * 8;

    const _Float16* asrc = split ? s_wlo : s_whi;
    const unsigned short* em_b = em + (size_t)bg4 * DP;

    // LDS fragment row bases (f16 units)
    const int arow0 = (ch * 32 + col) * 64;
    const int arow1 = (ch * 32 + 16 + col) * 64;
    const int brow0 = (kh * 32 + col) * 64;
    const int brow1 = (kh * 32 + 16 + col) * 64;

    for (int kb = 0; kb < NIT; ++kb) {
        const int k0 = kb * 64;
        stage16(whi + aoff + k0, s_whi + soff);
        stage16(wlo + aoff + k0, s_wlo + soff);
        stage16(cbp + boff + k0, s_cb  + soff);
        if (tid < 32) {  // 4 b x 64 ushort masks = 512 B
            const u32x4v mv = *(const u32x4v*)(em_b + (size_t)(tid >> 3) * DP + k0 + (tid & 7) * 8);
            *(u32x4v*)(s_mask + (tid >> 3) * 64 + (tid & 7) * 8) = mv;
        }
        __syncthreads();

        #pragma unroll
        for (int k2 = 0; k2 < 2; ++k2) {
            const int chunk = k2 * 4 + quad;
            const int sw    = (chunk ^ (col & 7)) * 8;
            const u32x4v a0 = *(const u32x4v*)(asrc + arow0 + sw);
            const u32x4v a1 = *(const u32x4v*)(asrc + arow1 + sw);
            const u32x4v b0 = *(const u32x4v*)(s_cb + brow0 + sw);
            const u32x4v b1 = *(const u32x4v*)(s_cb + brow1 + sw);
            const half8 af0 = __builtin_bit_cast(half8, a0);
            const half8 af1 = __builtin_bit_cast(half8, a1);
            #pragma unroll
            for (int b = 0; b < 4; ++b) {
                const u32x4v mr = *(const u32x4v*)(s_mask + b * 64 + chunk * 8);  // quad-broadcast
                const half8 bs0 = __builtin_bit_cast(half8, b0 ^ mr);
                const half8 bs1 = __builtin_bit_cast(half8, b1 ^ mr);
                acc[b][0][0] = __builtin_amdgcn_mfma_f32_16x16x32_f16(af0, bs0, acc[b][0][0], 0, 0, 0);
                acc[b][0][1] = __builtin_amdgcn_mfma_f32_16x16x32_f16(af0, bs1, acc[b][0][1], 0, 0, 0);
                acc[b][1][0] = __builtin_amdgcn_mfma_f32_16x16x32_f16(af1, bs0, acc[b][1][0], 0, 0, 0);
                acc[b][1][1] = __builtin_amdgcn_mfma_f32_16x16x32_f16(af1, bs1, acc[b][1][1], 0, 0, 0);
            }
        }
        __syncthreads();
    }

    // ---- epilogue: combine hi + lo*2^-12 via LDS (per b), then partial argmax ----
    // C/D layout (16x16): col = lane&15 (k), row = quad*4 + reg (c)
    float* fs = (float*)s_all;  // 4096 f32 = 16 KB scratch, region per (kh,ch)
    const int reg0 = (kh * 2 + ch) * 1024;
    #pragma unroll 1
    for (int b = 0; b < 4; ++b) {
        if (split == 1) {
            #pragma unroll
            for (int m = 0; m < 2; ++m)
                #pragma unroll
                for (int n = 0; n < 2; ++n)
                    *(f32x4*)(fs + reg0 + (m * 2 + n) * 256 + lane * 4) =
                        acc[b][m][n] * 0.000244140625f;  // lo * 2^-12 (exact)
        }
        __syncthreads();
        if (split == 0) {
            f32x4 s[2][2];
            #pragma unroll
            for (int m = 0; m < 2; ++m)
                #pragma unroll
                for (int n = 0; n < 2; ++n)
                    s[m][n] = acc[b][m][n] +
                              *(const f32x4*)(fs + reg0 + (m * 2 + n) * 256 + lane * 4);
            #pragma unroll
            for (int m = 0; m < 2; ++m) {
                #pragma unroll
                for (int r = 0; r < 4; ++r) {
                    float bv = -3.0e38f; int bk = 0x7fffffff;
                    #pragma unroll
                    for (int n = 0; n < 2; ++n) {
                        int kg = kr0 + kh * 32 + n * 16 + col;
                        float v = s[m][n][r];
                        if (kg < K_SZ && v > bv) { bv = v; bk = kg; }
                    }
                    #pragma unroll
                    for (int off = 1; off < 16; off <<= 1) {
                        float ov = __shfl_xor(bv, off, 64);
                        int   ok = __shfl_xor(bk, off, 64);
                        if (ov > bv || (ov == bv && ok < bk)) { bv = ov; bk = ok; }
                    }
                    if (col == 0) {
                        int crow = ch * 32 + m * 16 + quad * 4 + r;
                        s_argv[(b * 2 + kh) * 64 + crow] = bv;
                        s_argi[(b * 2 + kh) * 64 + crow] = bk;
                    }
                }
            }
        }
        __syncthreads();
    }
    if (tid < 256) {
        int b = tid >> 6, crow = tid & 63;
        float v0 = s_argv[(b * 2 + 0) * 64 + crow], v1 = s_argv[(b * 2 + 1) * 64 + crow];
        int   i0 = s_argi[(b * 2 + 0) * 64 + crow], i1 = s_argi[(b * 2 + 1) * 64 + crow];
        float bv; int bk;
        if (v1 > v0 || (v1 == v0 && i1 < i0)) { bv = v1; bk = i1; }
        else                                  { bv = v0; bk = i0; }
        int o = ((bg4 + b) * 8 + kt) * 128 + (c0 + crow);
        pval[o] = bv;
        pidx[o] = bk;
    }
}

// ---- final: reduce 8 kt partials per (b,c), map index -> temperature ----
__global__ void finalize_pred(const float* __restrict__ pval, const int* __restrict__ pidx,
                              float* __restrict__ out) {
    int t = blockIdx.x * 256 + threadIdx.x;
    if (t >= B_SZ * C_SZ) return;
    int b = t >> 7, c = t & 127;
    float bv = -3.0e38f; int bk = 0;
    #pragma unroll
    for (int nt = 0; nt < 8; ++nt) {
        int o = (b * 8 + nt) * 128 + c;
        float v = pval[o]; int k = pidx[o];
        if (v > bv || (v == bv && k < bk)) { bv = v; bk = k; }
    }
    out[t] = (float)bk / 499.0f * 61.5f + (-19.9f);
}

extern "C" void kernel_launch(void* const* d_in, const int* in_sizes, int n_in,
                              void* d_out, int out_size, void* d_ws, size_t ws_size,
                              hipStream_t stream) {
    const float* x    = (const float*)d_in[0];
    const float* wp   = (const float*)d_in[1];
    const float* bp   = (const float*)d_in[2];
    const float* wreg = (const float*)d_in[3];
    const float* cb   = (const float*)d_in[4];
    float* out = (float*)d_out;

    char* ws = (char*)d_ws;
    size_t o = 0;
    auto take = [&](size_t bytes) -> char* {
        o = (o + 255) & ~(size_t)255;
        char* p = ws + o;
        o += bytes;
        return p;
    };
    _Float16* whi       = (_Float16*)take(sizeof(_Float16) * C_SZ * DP);
    _Float16* wlo       = (_Float16*)take(sizeof(_Float16) * C_SZ * DP);
    _Float16* cbp       = (_Float16*)take(sizeof(_Float16) * KP * DP);
    unsigned short* em  = (unsigned short*)take(sizeof(unsigned short) * B_SZ * DP);
    float* pv           = (float*)take(sizeof(float) * B_SZ * 8 * C_SZ);
    int*   pi           = (int*)take(sizeof(int) * B_SZ * 8 * C_SZ);
    (void)ws_size; (void)in_sizes; (void)n_in; (void)out_size;

    prep_wsplit<<<(C_SZ * DP + 255) / 256, 256, 0, stream>>>(wreg, whi, wlo);
    prep_cb<<<(KP * DP + 255) / 256, 256, 0, stream>>>(cb, cbp);
    prep_enc<<<(B_SZ * DP + 255) / 256, 256, 0, stream>>>(x, wp, bp, em);

    dim3 g(16, 64);  // x: kt*2+ct, y: batch group
    gemm_argmax<<<g, 512, 0, stream>>>(whi, wlo, cbp, em, pv, pi);

    finalize_pred<<<(B_SZ * C_SZ + 255) / 256, 256, 0, stream>>>(pv, pi, out);
}

// Round 6
// 612.795 us; speedup vs baseline: 5.1995x; 5.0710x over previous
//
#include <hip/hip_runtime.h>
#include <math.h>

// Problem constants
#define B_SZ 256
#define S_SZ 6
#define D_SZ 10000
#define DP   10112      // D padded to 158*64
#define C_SZ 128
#define K_SZ 500
#define KP   512        // codebook rows padded (8 k-tiles of 64)
#define NIT  (DP / 64)  // 158 K-iterations

typedef _Float16     half8  __attribute__((ext_vector_type(8)));
typedef float        f32x4  __attribute__((ext_vector_type(4)));
typedef unsigned int u32x4v __attribute__((ext_vector_type(4)));

__device__ __forceinline__ void stage16(const void* g, void* l) {
    __builtin_amdgcn_global_load_lds(
        (const __attribute__((address_space(1))) unsigned int*)g,
        (__attribute__((address_space(3))) unsigned int*)l, 16, 0, 0);
}

// ---- prep: split W_reg (fp32) into f16 hi + f16 lo*4096 ----
__global__ void prep_wsplit(const float* __restrict__ wreg,
                            _Float16* __restrict__ whi, _Float16* __restrict__ wlo) {
    int t = blockIdx.x * 256 + threadIdx.x;
    if (t >= C_SZ * DP) return;
    int c = t / DP, d = t - c * DP;
    float w = (d < D_SZ) ? wreg[c * D_SZ + d] : 0.0f;
    _Float16 hi = (_Float16)w;
    float r = w - (float)hi;
    _Float16 lo = (_Float16)(r * 4096.0f);
    whi[t] = hi;
    wlo[t] = lo;
}

// ---- prep: codebook (±1 fp32) -> f16, zero-padded to [512][DP] ----
__global__ void prep_cb(const float* __restrict__ cb, _Float16* __restrict__ cbp) {
    int t = blockIdx.x * 256 + threadIdx.x;
    if (t >= KP * DP) return;
    int k = t / DP, d = t - k * DP;
    float v = (k < K_SZ && d < D_SZ) ? cb[k * D_SZ + d] : 0.0f;
    cbp[t] = (_Float16)v;
}

// ---- prep: enc sign mask (0x0000 = +1, 0x8000 = -1), fp64 for exact sign match ----
__global__ void prep_enc(const float* __restrict__ x, const float* __restrict__ wp,
                         const float* __restrict__ bp, unsigned short* __restrict__ em) {
    int t = blockIdx.x * 256 + threadIdx.x;
    if (t >= B_SZ * DP) return;
    int b = t / DP, d = t - b * DP;
    unsigned short m = 0;
    if (d < D_SZ) {
        double p = 0.0;
        #pragma unroll
        for (int s = 0; s < S_SZ; ++s)
            p += (double)x[b * S_SZ + s] * (double)wp[d * S_SZ + s];
        double hv = cos(p + (double)bp[d]) * sin(p);
        m = (hv > 0.0) ? (unsigned short)0u : (unsigned short)0x8000u;
    }
    em[t] = m;
}

// ---- main: block = 512 thr = 8 waves = (split x kh x ch); tile 4b x 64c x 64k.
// Each wave computes ONE split (hi or lo) of a 4b x 32c x 32k sub-tile -> 64 acc
// regs/wave. CRITICAL (R3/R4 post-mortem): every index into acc[][][] must be a
// compile-time constant — a single runtime-indexed access (the old
// `#pragma unroll 1` epilogue loop) demotes the whole array to scratch:
// VGPR_Count=64 + 20.8 GB of HBM writeback, 6x regression. All loops touching
// acc are fully unrolled. No forced occupancy cap (launch_bounds(512) only).
// Signs XORed onto B (cb) fragments (bit-exact); masks staged in LDS, read as
// quad-broadcast b128. LDS XOR-swizzled: chunk p of row r holds chunk (p^(r&7)).
__global__ __launch_bounds__(512) void gemm_argmax(
    const _Float16* __restrict__ whi, const _Float16* __restrict__ wlo,
    const _Float16* __restrict__ cbp, const unsigned short* __restrict__ em,
    float* __restrict__ pval, int* __restrict__ pidx)
{
    const int kt = blockIdx.x >> 1;   // 0..7  k-tile (64 codebook rows)
    const int ct = blockIdx.x & 1;    // 0..1  c-tile (64 classes)
    const int bg = blockIdx.y;        // 0..63 batch group (4 batches)
    const int tid   = threadIdx.x;
    const int wave  = tid >> 6;
    const int lane  = tid & 63;
    const int quad  = lane >> 4;
    const int col   = lane & 15;
    const int ch    = wave & 1;         // c half (32 rows)
    const int kh    = (wave >> 1) & 1;  // k half (32 cols)
    const int split = wave >> 2;        // 0 = hi, 1 = lo

    __shared__ __align__(16) _Float16 s_all[3 * 4096];  // whi | wlo | cb, 8 KB each
    __shared__ __align__(16) unsigned short s_mask[4 * 64];
    __shared__ __align__(16) float s_argv[4 * 2 * 64];  // [b][kh][crow]
    __shared__ __align__(16) int   s_argi[4 * 2 * 64];

    _Float16* s_whi = s_all;
    _Float16* s_wlo = s_all + 4096;
    _Float16* s_cb  = s_all + 8192;

    f32x4 acc[4][2][2];
    #pragma unroll
    for (int b = 0; b < 4; ++b)
        #pragma unroll
        for (int m = 0; m < 2; ++m)
            #pragma unroll
            for (int n = 0; n < 2; ++n)
                acc[b][m][n] = (f32x4){0.f, 0.f, 0.f, 0.f};

    const int c0  = ct * 64;
    const int kr0 = kt * 64;
    const int bg4 = bg * 4;

    // staging: each thread stages exactly one 16-B chunk of each array per iter
    const int srow = tid >> 3;
    const int sp   = tid & 7;
    const int sgc  = (sp ^ (srow & 7)) * 8;       // swizzled global f16 col
    const size_t aoff = (size_t)(c0 + srow) * DP + sgc;
    const size_t boff = (size_t)(kr0 + srow) * DP + sgc;
    const int soff = tid * 8;

    const _Float16* asrc = split ? s_wlo : s_whi;
    const unsigned short* em_b = em + (size_t)bg4 * DP;

    // LDS fragment row bases (f16 units)
    const int arow0 = (ch * 32 + col) * 64;
    const int arow1 = (ch * 32 + 16 + col) * 64;
    const int brow0 = (kh * 32 + col) * 64;
    const int brow1 = (kh * 32 + 16 + col) * 64;

    for (int kb = 0; kb < NIT; ++kb) {
        const int k0 = kb * 64;
        stage16(whi + aoff + k0, s_whi + soff);
        stage16(wlo + aoff + k0, s_wlo + soff);
        stage16(cbp + boff + k0, s_cb  + soff);
        if (tid < 32) {  // 4 b x 64 ushort masks = 512 B
            const u32x4v mv = *(const u32x4v*)(em_b + (size_t)(tid >> 3) * DP + k0 + (tid & 7) * 8);
            *(u32x4v*)(s_mask + (tid >> 3) * 64 + (tid & 7) * 8) = mv;
        }
        __syncthreads();

        #pragma unroll
        for (int k2 = 0; k2 < 2; ++k2) {
            const int chunk = k2 * 4 + quad;
            const int sw    = (chunk ^ (col & 7)) * 8;
            const u32x4v a0 = *(const u32x4v*)(asrc + arow0 + sw);
            const u32x4v a1 = *(const u32x4v*)(asrc + arow1 + sw);
            const u32x4v b0 = *(const u32x4v*)(s_cb + brow0 + sw);
            const u32x4v b1 = *(const u32x4v*)(s_cb + brow1 + sw);
            const half8 af0 = __builtin_bit_cast(half8, a0);
            const half8 af1 = __builtin_bit_cast(half8, a1);
            #pragma unroll
            for (int b = 0; b < 4; ++b) {
                const u32x4v mr = *(const u32x4v*)(s_mask + b * 64 + chunk * 8);  // quad-broadcast
                const half8 bs0 = __builtin_bit_cast(half8, b0 ^ mr);
                const half8 bs1 = __builtin_bit_cast(half8, b1 ^ mr);
                acc[b][0][0] = __builtin_amdgcn_mfma_f32_16x16x32_f16(af0, bs0, acc[b][0][0], 0, 0, 0);
                acc[b][0][1] = __builtin_amdgcn_mfma_f32_16x16x32_f16(af0, bs1, acc[b][0][1], 0, 0, 0);
                acc[b][1][0] = __builtin_amdgcn_mfma_f32_16x16x32_f16(af1, bs0, acc[b][1][0], 0, 0, 0);
                acc[b][1][1] = __builtin_amdgcn_mfma_f32_16x16x32_f16(af1, bs1, acc[b][1][1], 0, 0, 0);
            }
        }
        __syncthreads();
    }

    // ---- epilogue: combine hi + lo*2^-12 via LDS (per b), then partial argmax ----
    // C/D layout (16x16): col = lane&15 (k), row = quad*4 + reg (c)
    // FULLY UNROLLED over b: acc indices must stay compile-time constants.
    float* fs = (float*)s_all;  // 4096 f32 = 16 KB scratch, region per (kh,ch)
    const int reg0 = (kh * 2 + ch) * 1024;
    #pragma unroll
    for (int b = 0; b < 4; ++b) {
        if (split == 1) {
            #pragma unroll
            for (int m = 0; m < 2; ++m)
                #pragma unroll
                for (int n = 0; n < 2; ++n)
                    *(f32x4*)(fs + reg0 + (m * 2 + n) * 256 + lane * 4) =
                        acc[b][m][n] * 0.000244140625f;  // lo * 2^-12 (exact)
        }
        __syncthreads();
        if (split == 0) {
            f32x4 s[2][2];
            #pragma unroll
            for (int m = 0; m < 2; ++m)
                #pragma unroll
                for (int n = 0; n < 2; ++n)
                    s[m][n] = acc[b][m][n] +
                              *(const f32x4*)(fs + reg0 + (m * 2 + n) * 256 + lane * 4);
            #pragma unroll
            for (int m = 0; m < 2; ++m) {
                #pragma unroll
                for (int r = 0; r < 4; ++r) {
                    float bv = -3.0e38f; int bk = 0x7fffffff;
                    #pragma unroll
                    for (int n = 0; n < 2; ++n) {
                        int kg = kr0 + kh * 32 + n * 16 + col;
                        float v = s[m][n][r];
                        if (kg < K_SZ && v > bv) { bv = v; bk = kg; }
                    }
                    #pragma unroll
                    for (int off = 1; off < 16; off <<= 1) {
                        float ov = __shfl_xor(bv, off, 64);
                        int   ok = __shfl_xor(bk, off, 64);
                        if (ov > bv || (ov == bv && ok < bk)) { bv = ov; bk = ok; }
                    }
                    if (col == 0) {
                        int crow = ch * 32 + m * 16 + quad * 4 + r;
                        s_argv[(b * 2 + kh) * 64 + crow] = bv;
                        s_argi[(b * 2 + kh) * 64 + crow] = bk;
                    }
                }
            }
        }
        __syncthreads();
    }
    if (tid < 256) {
        int b = tid >> 6, crow = tid & 63;
        float v0 = s_argv[(b * 2 + 0) * 64 + crow], v1 = s_argv[(b * 2 + 1) * 64 + crow];
        int   i0 = s_argi[(b * 2 + 0) * 64 + crow], i1 = s_argi[(b * 2 + 1) * 64 + crow];
        float bv; int bk;
        if (v1 > v0 || (v1 == v0 && i1 < i0)) { bv = v1; bk = i1; }
        else                                  { bv = v0; bk = i0; }
        int o = ((bg4 + b) * 8 + kt) * 128 + (c0 + crow);
        pval[o] = bv;
        pidx[o] = bk;
    }
}

// ---- final: reduce 8 kt partials per (b,c), map index -> temperature ----
__global__ void finalize_pred(const float* __restrict__ pval, const int* __restrict__ pidx,
                              float* __restrict__ out) {
    int t = blockIdx.x * 256 + threadIdx.x;
    if (t >= B_SZ * C_SZ) return;
    int b = t >> 7, c = t & 127;
    float bv = -3.0e38f; int bk = 0;
    #pragma unroll
    for (int nt = 0; nt < 8; ++nt) {
        int o = (b * 8 + nt) * 128 + c;
        float v = pval[o]; int k = pidx[o];
        if (v > bv || (v == bv && k < bk)) { bv = v; bk = k; }
    }
    out[t] = (float)bk / 499.0f * 61.5f + (-19.9f);
}

extern "C" void kernel_launch(void* const* d_in, const int* in_sizes, int n_in,
                              void* d_out, int out_size, void* d_ws, size_t ws_size,
                              hipStream_t stream) {
    const float* x    = (const float*)d_in[0];
    const float* wp   = (const float*)d_in[1];
    const float* bp   = (const float*)d_in[2];
    const float* wreg = (const float*)d_in[3];
    const float* cb   = (const float*)d_in[4];
    float* out = (float*)d_out;

    char* ws = (char*)d_ws;
    size_t o = 0;
    auto take = [&](size_t bytes) -> char* {
        o = (o + 255) & ~(size_t)255;
        char* p = ws + o;
        o += bytes;
        return p;
    };
    _Float16* whi       = (_Float16*)take(sizeof(_Float16) * C_SZ * DP);
    _Float16* wlo       = (_Float16*)take(sizeof(_Float16) * C_SZ * DP);
    _Float16* cbp       = (_Float16*)take(sizeof(_Float16) * KP * DP);
    unsigned short* em  = (unsigned short*)take(sizeof(unsigned short) * B_SZ * DP);
    float* pv           = (float*)take(sizeof(float) * B_SZ * 8 * C_SZ);
    int*   pi           = (int*)take(sizeof(int) * B_SZ * 8 * C_SZ);
    (void)ws_size; (void)in_sizes; (void)n_in; (void)out_size;

    prep_wsplit<<<(C_SZ * DP + 255) / 256, 256, 0, stream>>>(wreg, whi, wlo);
    prep_cb<<<(KP * DP + 255) / 256, 256, 0, stream>>>(cb, cbp);
    prep_enc<<<(B_SZ * DP + 255) / 256, 256, 0, stream>>>(x, wp, bp, em);

    dim3 g(16, 64);  // x: kt*2+ct, y: batch group
    gemm_argmax<<<g, 512, 0, stream>>>(whi, wlo, cbp, em, pv, pi);

    finalize_pred<<<(B_SZ * C_SZ + 255) / 256, 256, 0, stream>>>(pv, pi, out);
}